// Round 7
// baseline (59.517 us; speedup 1.0000x reference)
//
#include <hip/hip_runtime.h>
#include <stdint.h>

#define B_N   65536
#define NIC   64
#define NIW   64
#define NH    128
#define NA    5
#define D2    128   // 2*NIC

#define PARTITIONABLE 1

#define NBLK  512   // fused row-blocks (128 rows each)

// ws layout (ushort units): expert frags [0, 5*24576); Wp1h [122880, +16384);
// Wp1l [139264, +16384). Total 311296 bytes << ws_size (512 MB confirmed).
#define WP_EXPERT   0
#define WP_W1H      (NA * 24576)
#define WP_W1L      (WP_W1H + 16384)

typedef __attribute__((ext_vector_type(8))) short short8;
typedef __attribute__((ext_vector_type(4))) float f32x4;

__device__ __forceinline__ ushort f2bf(float f) {
  uint32_t u = __float_as_uint(f);
  uint32_t r = (u + 0x7FFFu + ((u >> 16) & 1u)) >> 16;  // RNE
  return (ushort)r;
}

__device__ __forceinline__ void split2(float f, ushort& h, ushort& l) {
  h = f2bf(f);
  l = f2bf(f - __uint_as_float(((uint32_t)h) << 16));
}

__device__ __forceinline__ void threefry2x32_k042(uint32_t x0, uint32_t x1,
                                                  uint32_t& o0, uint32_t& o1) {
  const uint32_t ks0 = 0u;
  const uint32_t ks1 = 42u;
  const uint32_t ks2 = 0x1BD11BDAu ^ 0u ^ 42u;
  x0 += ks0; x1 += ks1;
#define TF_RND(r) { x0 += x1; x1 = (x1 << (r)) | (x1 >> (32 - (r))); x1 ^= x0; }
  TF_RND(13) TF_RND(15) TF_RND(26) TF_RND(6)
  x0 += ks1; x1 += ks2 + 1u;
  TF_RND(17) TF_RND(29) TF_RND(16) TF_RND(24)
  x0 += ks2; x1 += ks0 + 2u;
  TF_RND(13) TF_RND(15) TF_RND(26) TF_RND(6)
  x0 += ks0; x1 += ks1 + 3u;
  TF_RND(17) TF_RND(29) TF_RND(16) TF_RND(24)
  x0 += ks1; x1 += ks2 + 4u;
  TF_RND(13) TF_RND(15) TF_RND(26) TF_RND(6)
  x0 += ks2; x1 += ks0 + 5u;
#undef TF_RND
  o0 = x0; o1 = x1;
}

__device__ __forceinline__ float gumbel_at(uint32_t idx) {
  uint32_t bits;
#if PARTITIONABLE
  uint32_t a, b;
  threefry2x32_k042(0u, idx, a, b);
  bits = a ^ b;
#else
  const uint32_t HALF = (uint32_t)(B_N * NA) / 2u;
  uint32_t a, b;
  if (idx < HALF) { threefry2x32_k042(idx, idx + HALF, a, b); bits = a; }
  else            { threefry2x32_k042(idx - HALF, idx, a, b); bits = b; }
#endif
  const float f = __uint_as_float((bits >> 9) | 0x3f800000u) - 1.0f;
  const double u = (f == 0.0f) ? (double)0x1p-126 : (double)f;
  const float nl = (float)(-log(u));
  const float g  = (float)(-log((double)nl));
  return g;
}

// ---------------- K1: prepack weights into bf16 fragment order --------------
// blocks 0..4: expert a (verbatim, proven); block 5: Wp1 hi/lo frags.
__global__ __launch_bounds__(512, 1) void prepack_kernel(
    const float* __restrict__ Wp1, const float* __restrict__ We1,
    const float* __restrict__ We2, ushort* __restrict__ wPrep) {
  const int tid = threadIdx.x;
  if (blockIdx.x < NA) {
    const int a = blockIdx.x;
    ushort* wp = wPrep + (size_t)a * 24576;
    {
      const float* W1g = We1 + (size_t)a * D2 * NH;
      const int n = tid & 127, q = tid >> 7;
      const int fb = (n >> 4) * 4 + q;
      const int cc = n & 15;
#pragma unroll
      for (int grp = 0; grp < 4; grp++) {
        short8 pk;
#pragma unroll
        for (int j = 0; j < 8; j++)
          pk[j] = (short)f2bf(W1g[(32 * q + 8 * grp + j) * NH + n]);
        *(short8*)&wp[fb * 512 + (cc + 16 * grp) * 8] = pk;
      }
    }
    {
      const float* W2g = We2 + (size_t)a * NH * NIW;
      const int o = tid & 63, hq = tid >> 6;
      const int fb = (o >> 4) * 4 + (hq >> 1);
      const int cc = o & 15;
#pragma unroll
      for (int g2 = 0; g2 < 2; g2++) {
        const int grp = (hq & 1) * 2 + g2;
        short8 pk;
#pragma unroll
        for (int j = 0; j < 8; j++)
          pk[j] = (short)f2bf(W2g[(16 * hq + 8 * g2 + j) * NIW + o]);
        *(short8*)&wp[16384 + fb * 512 + (cc + 16 * grp) * 8] = pk;
      }
    }
  } else {
    // Wp1 -> hi/lo fragment order in global (same mapping as old LDS staging)
    ushort* wh = wPrep + WP_W1H;
    ushort* wl = wPrep + WP_W1L;
    const int n = tid & 127, q = tid >> 7;
    const int fb = (n >> 4) * 4 + q;
    const int cc = n & 15;
#pragma unroll
    for (int grp = 0; grp < 4; grp++) {
      short8 ph, pl;
#pragma unroll
      for (int j = 0; j < 8; j++) {
        const int k = 32 * q + 8 * grp + j;
        ushort hh, ll;
        split2(Wp1[k * NH + n], hh, ll);
        ph[j] = (short)hh;
        pl[j] = (short)ll;
      }
      *(short8*)&wh[fb * 512 + (cc + 16 * grp) * 8] = ph;
      *(short8*)&wl[fb * 512 + (cc + 16 * grp) * 8] = pl;
    }
  }
}

// ---------------- K2: fused policy + categorical + expert + wemb ------------
__global__ __launch_bounds__(512, 4) void fused_kernel(
    const int* __restrict__ x, const int* __restrict__ y,
    const float* __restrict__ cemb, const float* __restrict__ wemb,
    const float* __restrict__ bp1, const float* __restrict__ Wp2,
    const float* __restrict__ bp2, const float* __restrict__ be1,
    const float* __restrict__ be2, const ushort* __restrict__ wPrep,
    float* __restrict__ out, float* __restrict__ out_wemb) {
  // region: h as f32 [128][132] during policy; per-wave Ht (bf16) during expert
  __shared__ __align__(16) uint8_t region8[67584];
  __shared__ __align__(16) float sW2t[NA][NH];
  __shared__ __align__(16) float sb1[NH];
  __shared__ __align__(16) float sScore[128][NA];
  __shared__ __align__(16) float sbe1f[NA * NH];
  __shared__ __align__(16) float sbe2f[NA * NIW];
  __shared__ int sList[NA][128];
  __shared__ int sCnt[NA];

  float (*sCH)[132] = (float (*)[132])region8;

  const int tid = threadIdx.x;
  const int base = blockIdx.x * 128;

  // ---- P0: stage small tables; wemb gather; build policy A-frags ----
  if (tid < NH) sb1[tid] = bp1[tid];
  if (tid < NA * 32) {
    const int a = tid >> 5, k0 = (tid & 31) * 4;
#pragma unroll
    for (int j = 0; j < 4; j++) sW2t[a][k0 + j] = Wp2[(k0 + j) * NA + a];
  }
  if (tid < NA) sCnt[tid] = 0;
  for (int i = tid; i < NA * NH; i += 512) sbe1f[i] = be1[i];
  for (int i = tid; i < NA * NIW; i += 512) sbe2f[i] = be2[i];

#pragma unroll 1
  for (int i = tid; i < 128 * 16; i += 512) {
    const int row = i >> 4, seg = i & 15;
    ((float4*)out_wemb)[(size_t)(base + row) * 16 + seg] =
        ((const float4*)wemb)[(size_t)y[base + row] * 16 + seg];
  }

  const int wave = tid >> 6, lane = tid & 63;
  const int c16 = lane & 15, h2 = lane >> 4;

  const int rloc = wave * 16 + c16;
  const int grow = base + rloc;
  const int xi0 = x[grow * 2], xi1 = x[grow * 2 + 1];
  short8 Ah[4], Al[4];
#pragma unroll
  for (int kt = 0; kt < 4; kt++) {
    const int xi = (kt < 2) ? xi0 : xi1;
    const float* src = cemb + (size_t)xi * NIC + (kt & 1) * 32 + h2 * 8;
    const float4 aa = *(const float4*)src;
    const float4 bb = *(const float4*)(src + 4);
    ushort hh, ll;
    short8 ph, pl;
    split2(aa.x, hh, ll); ph[0] = (short)hh; pl[0] = (short)ll;
    split2(aa.y, hh, ll); ph[1] = (short)hh; pl[1] = (short)ll;
    split2(aa.z, hh, ll); ph[2] = (short)hh; pl[2] = (short)ll;
    split2(aa.w, hh, ll); ph[3] = (short)hh; pl[3] = (short)ll;
    split2(bb.x, hh, ll); ph[4] = (short)hh; pl[4] = (short)ll;
    split2(bb.y, hh, ll); ph[5] = (short)hh; pl[5] = (short)ll;
    split2(bb.z, hh, ll); ph[6] = (short)hh; pl[6] = (short)ll;
    split2(bb.w, hh, ll); ph[7] = (short)hh; pl[7] = (short)ll;
    Ah[kt] = ph;
    Al[kt] = pl;
  }
  __syncthreads();   // sb1 ready

  // ---- P1: policy L1, 3-term split-bf16 MFMA; B-frags from global ----
  const ushort* wp1h = wPrep + WP_W1H;
  const ushort* wp1l = wPrep + WP_W1L;
  {
    const int rowb = wave * 16 + h2 * 4;
#pragma unroll
    for (int half = 0; half < 2; half++) {   // 4 ct at a time (VGPR <= 128)
      f32x4 acc[4];
#pragma unroll
      for (int c2 = 0; c2 < 4; c2++) {
        const float bv = sb1[(half * 4 + c2) * 16 + c16];
        acc[c2] = (f32x4){bv, bv, bv, bv};
      }
#pragma unroll
      for (int kt = 0; kt < 4; kt++) {
#pragma unroll
        for (int c2 = 0; c2 < 4; c2++) {
          const int fb = (half * 4 + c2) * 4 + kt;
          const short8 Bh = *(const short8*)&wp1h[fb * 512 + lane * 8];
          const short8 Bl = *(const short8*)&wp1l[fb * 512 + lane * 8];
          acc[c2] = __builtin_amdgcn_mfma_f32_16x16x32_bf16(Ah[kt], Bh, acc[c2], 0, 0, 0);
          acc[c2] = __builtin_amdgcn_mfma_f32_16x16x32_bf16(Al[kt], Bh, acc[c2], 0, 0, 0);
          acc[c2] = __builtin_amdgcn_mfma_f32_16x16x32_bf16(Ah[kt], Bl, acc[c2], 0, 0, 0);
        }
      }
#pragma unroll
      for (int c2 = 0; c2 < 4; c2++) {
        const int n = (half * 4 + c2) * 16 + c16;
#pragma unroll
        for (int r = 0; r < 4; r++)
          sCH[rowb + r][n] = fmaxf(acc[c2][r], 0.0f);   // wave-owned rows
      }
    }
  }
  __syncthreads();

  // ---- P2: logits + gumbel scores (verbatim proven epilogue) ----
#pragma unroll 1
  for (int p = tid; p < 128 * NA; p += 512) {
    const int row = p / NA, a = p - NA * row;
    float s0 = 0.f, s1 = 0.f, s2 = 0.f, s3 = 0.f;
#pragma unroll 4
    for (int k = 0; k < NH; k += 4) {
      const float4 h4 = *(const float4*)&sCH[row][k];
      const float4 w4 = *(const float4*)&sW2t[a][k];
      s0 = fmaf(h4.x, w4.x, s0);
      s1 = fmaf(h4.y, w4.y, s1);
      s2 = fmaf(h4.z, w4.z, s2);
      s3 = fmaf(h4.w, w4.w, s3);
    }
    const float logit = ((s0 + s1) + (s2 + s3)) + bp2[a];
    sScore[row][a] = gumbel_at((uint32_t)((base + row) * NA + a)) + logit;
  }
  __syncthreads();

  // ---- argmax + local bucketing ----
  if (tid < 128) {
    int best = 0;
    float bs = sScore[tid][0];
#pragma unroll
    for (int a = 1; a < NA; a++) {
      const float s = sScore[tid][a];
      if (s > bs) { bs = s; best = a; }
    }
    const int p = atomicAdd(&sCnt[best], 1);
    sList[best][p] = tid;
  }
  __syncthreads();

  const int c0 = sCnt[0], c1 = sCnt[1], c2_ = sCnt[2], c3 = sCnt[3], c4 = sCnt[4];
  const int p1 = (c0 + 15) >> 4;
  const int p2 = p1 + ((c1 + 15) >> 4);
  const int p3 = p2 + ((c2_ + 15) >> 4);
  const int p4 = p3 + ((c3 + 15) >> 4);
  const int T  = p4 + ((c4 + 15) >> 4);

  const int rowb = h2 * 4;
  ushort* myHt = (ushort*)region8 + wave * 2048;   // overlays dead sCH

  // ---- P3: expert loop (round-4/6 verbatim core; A-frags re-gathered) ----
#pragma unroll 1
  for (int t = wave; t < T; t += 8) {
    int a = 0, ti = t, cnt = c0;
    if (t >= p1) { a = 1; ti = t - p1; cnt = c1; }
    if (t >= p2) { a = 2; ti = t - p2; cnt = c2_; }
    if (t >= p3) { a = 3; ti = t - p3; cnt = c3; }
    if (t >= p4) { a = 4; ti = t - p4; cnt = c4; }
    const ushort* wp1 = wPrep + (size_t)a * 24576;
    const ushort* wp2 = wp1 + 16384;

    const int slot = ti * 16 + c16;
    const int rl = sList[a][(slot < cnt) ? slot : 0];
    const int2 xi2 = ((const int2*)x)[base + rl];
    short8 Ae[4];
#pragma unroll
    for (int kt = 0; kt < 4; kt++) {
      const float* src = cemb + (size_t)((kt < 2) ? xi2.x : xi2.y) * NIC +
                         (kt & 1) * 32 + h2 * 8;
      const float4 aa = *(const float4*)src;
      const float4 bb = *(const float4*)(src + 4);
      short8 pk;
      pk[0] = (short)f2bf(aa.x); pk[1] = (short)f2bf(aa.y);
      pk[2] = (short)f2bf(aa.z); pk[3] = (short)f2bf(aa.w);
      pk[4] = (short)f2bf(bb.x); pk[5] = (short)f2bf(bb.y);
      pk[6] = (short)f2bf(bb.z); pk[7] = (short)f2bf(bb.w);
      Ae[kt] = pk;
    }

#pragma unroll
    for (int ct = 0; ct < 8; ct++) {
      const float bv = sbe1f[a * NH + ct * 16 + c16];
      f32x4 ac = {bv, bv, bv, bv};
#pragma unroll
      for (int kt = 0; kt < 4; kt++) {
        const short8 Bf = *(const short8*)&wp1[(ct * 4 + kt) * 512 + lane * 8];
        ac = __builtin_amdgcn_mfma_f32_16x16x32_bf16(Ae[kt], Bf, ac, 0, 0, 0);
      }
      const int n = ct * 16 + c16;
      const int kt2 = n >> 5, grp2 = (n & 31) >> 3, j2 = n & 7;
#pragma unroll
      for (int r = 0; r < 4; r++)
        myHt[kt2 * 512 + ((rowb + r) + 16 * grp2) * 8 + j2] =
            f2bf(fmaxf(ac[r], 0.0f));
    }

    short8 A2[4];
#pragma unroll
    for (int kt = 0; kt < 4; kt++)
      A2[kt] = *(const short8*)&myHt[kt * 512 + lane * 8];
    int gr4[4];
#pragma unroll
    for (int r = 0; r < 4; r++) {
      const int li2 = ti * 16 + rowb + r;
      gr4[r] = (li2 < cnt) ? sList[a][li2] : -1;
    }
#pragma unroll
    for (int ot = 0; ot < 4; ot++) {
      const float bv = sbe2f[a * NIW + ot * 16 + c16];
      f32x4 o4 = {bv, bv, bv, bv};
#pragma unroll
      for (int kt = 0; kt < 4; kt++) {
        const short8 Bf = *(const short8*)&wp2[(ot * 4 + kt) * 512 + lane * 8];
        o4 = __builtin_amdgcn_mfma_f32_16x16x32_bf16(A2[kt], Bf, o4, 0, 0, 0);
      }
#pragma unroll
      for (int r = 0; r < 4; r++)
        if (gr4[r] >= 0)
          out[(size_t)(base + gr4[r]) * NIW + ot * 16 + c16] = o4[r];
    }
  }
}

extern "C" void kernel_launch(void* const* d_in, const int* in_sizes, int n_in,
                              void* d_out, int out_size, void* d_ws, size_t ws_size,
                              hipStream_t stream) {
  const int*   x    = (const int*)d_in[0];
  const int*   y    = (const int*)d_in[1];
  const float* cemb = (const float*)d_in[2];
  const float* wemb = (const float*)d_in[3];
  const float* Wp1  = (const float*)d_in[4];
  const float* bp1  = (const float*)d_in[5];
  const float* Wp2  = (const float*)d_in[6];
  const float* bp2  = (const float*)d_in[7];
  const float* We1  = (const float*)d_in[8];
  const float* be1  = (const float*)d_in[9];
  const float* We2  = (const float*)d_in[10];
  const float* be2  = (const float*)d_in[11];

  float* out      = (float*)d_out;
  float* out_wemb = out + (size_t)B_N * NIW;
  ushort* wPrep   = (ushort*)d_ws;   // 311296 bytes; ws_size = 512 MB

  prepack_kernel<<<NA + 1, 512, 0, stream>>>(Wp1, We1, We2, wPrep);
  fused_kernel<<<NBLK, 512, 0, stream>>>(
      x, y, cemb, wemb, bp1, Wp2, bp2, be1, be2, wPrep, out, out_wemb);
}

// Round 8
// 42.346 us; speedup vs baseline: 1.4055x; 1.4055x over previous
//
#include <hip/hip_runtime.h>
#include <stdint.h>

#define B_N   65536
#define NIC   64
#define NIW   64
#define NH    128
#define NA    5
#define D2    128   // 2*NIC

#define PARTITIONABLE 1

#define P2_NCHUNK 51
#define P2_R      1286  // ceil(B_N / P2_NCHUNK)

typedef __attribute__((ext_vector_type(8))) short short8;
typedef __attribute__((ext_vector_type(4))) float f32x4;

__device__ __forceinline__ ushort f2bf(float f) {
  uint32_t u = __float_as_uint(f);
  uint32_t r = (u + 0x7FFFu + ((u >> 16) & 1u)) >> 16;  // RNE
  return (ushort)r;
}

__device__ __forceinline__ void split2(float f, ushort& h, ushort& l) {
  h = f2bf(f);
  l = f2bf(f - __uint_as_float(((uint32_t)h) << 16));
}

__device__ __forceinline__ void threefry2x32_k042(uint32_t x0, uint32_t x1,
                                                  uint32_t& o0, uint32_t& o1) {
  const uint32_t ks0 = 0u;
  const uint32_t ks1 = 42u;
  const uint32_t ks2 = 0x1BD11BDAu ^ 0u ^ 42u;
  x0 += ks0; x1 += ks1;
#define TF_RND(r) { x0 += x1; x1 = (x1 << (r)) | (x1 >> (32 - (r))); x1 ^= x0; }
  TF_RND(13) TF_RND(15) TF_RND(26) TF_RND(6)
  x0 += ks1; x1 += ks2 + 1u;
  TF_RND(17) TF_RND(29) TF_RND(16) TF_RND(24)
  x0 += ks2; x1 += ks0 + 2u;
  TF_RND(13) TF_RND(15) TF_RND(26) TF_RND(6)
  x0 += ks0; x1 += ks1 + 3u;
  TF_RND(17) TF_RND(29) TF_RND(16) TF_RND(24)
  x0 += ks1; x1 += ks2 + 4u;
  TF_RND(13) TF_RND(15) TF_RND(26) TF_RND(6)
  x0 += ks2; x1 += ks0 + 5u;
#undef TF_RND
  o0 = x0; o1 = x1;
}

__device__ __forceinline__ float gumbel_at(uint32_t idx) {
  uint32_t bits;
#if PARTITIONABLE
  uint32_t a, b;
  threefry2x32_k042(0u, idx, a, b);
  bits = a ^ b;
#else
  const uint32_t HALF = (uint32_t)(B_N * NA) / 2u;
  uint32_t a, b;
  if (idx < HALF) { threefry2x32_k042(idx, idx + HALF, a, b); bits = a; }
  else            { threefry2x32_k042(idx - HALF, idx, a, b); bits = b; }
#endif
  const float f = __uint_as_float((bits >> 9) | 0x3f800000u) - 1.0f;
  const double u = (f == 0.0f) ? (double)0x1p-126 : (double)f;
  const float nl = (float)(-log(u));
  const float g  = (float)(-log((double)nl));
  return g;
}

// ---------------- Phase 1: policy MLP, in-register epilogue -----------------
// A-frag: row = lane&15, k = 32*kt + 8*(lane>>4) + j
// D     : col = ct*16 + (lane&15), row(local16) = (lane>>4)*4 + r
__global__ __launch_bounds__(512, 4) void policy_kernel(
    const int* __restrict__ x, const int* __restrict__ y,
    const float* __restrict__ cemb, const float* __restrict__ wemb,
    const float* __restrict__ Wp1, const float* __restrict__ bp1,
    const float* __restrict__ Wp2, const float* __restrict__ bp2,
    float* __restrict__ out_wemb, int* __restrict__ action) {
  __shared__ __align__(16) ushort sW1h[16384];   // 32 KB Wp1 hi frags
  __shared__ __align__(16) ushort sW1l[16384];   // 32 KB Wp1 lo frags
  __shared__ __align__(16) float sW2t[NA][NH];   // Wp2^T
  __shared__ __align__(16) float sb1[NH];
  __shared__ __align__(16) float sbp2[8];

  const int tid = threadIdx.x;
  const int base = blockIdx.x * 128;

  // ---- stage Wp1 hi/lo frags (verbatim proven), small tables ----
  {
    const int n = tid & 127, q = tid >> 7;
    const int fb = (n >> 4) * 4 + q;
    const int cc = n & 15;
#pragma unroll
    for (int grp = 0; grp < 4; grp++) {
      short8 ph, pl;
#pragma unroll
      for (int j = 0; j < 8; j++) {
        const int k = 32 * q + 8 * grp + j;
        ushort hh, ll;
        split2(Wp1[k * NH + n], hh, ll);
        ph[j] = (short)hh;
        pl[j] = (short)ll;
      }
      *(short8*)&sW1h[fb * 512 + (cc + 16 * grp) * 8] = ph;
      *(short8*)&sW1l[fb * 512 + (cc + 16 * grp) * 8] = pl;
    }
    if (tid < NH) sb1[tid] = bp1[tid];
    if (tid < NA * 32) {
      const int a = tid >> 5, k0 = (tid & 31) * 4;
#pragma unroll
      for (int j = 0; j < 4; j++) sW2t[a][k0 + j] = Wp2[(k0 + j) * NA + a];
    }
    if (tid < NA) sbp2[tid] = bp2[tid];
  }

  const int wave = tid >> 6, lane = tid & 63;
  const int c16 = lane & 15, h2 = lane >> 4;

  // ---- build A-frags (hi/lo) in registers from cemb (verbatim) ----
  const int grow = base + wave * 16 + c16;
  const int xi0 = x[grow * 2], xi1 = x[grow * 2 + 1];
  short8 Ah[4], Al[4];
#pragma unroll
  for (int kt = 0; kt < 4; kt++) {
    const int xi = (kt < 2) ? xi0 : xi1;
    const float* src = cemb + (size_t)xi * NIC + (kt & 1) * 32 + h2 * 8;
    const float4 aa = *(const float4*)src;
    const float4 bb = *(const float4*)(src + 4);
    ushort hh, ll;
    short8 ph, pl;
    split2(aa.x, hh, ll); ph[0] = (short)hh; pl[0] = (short)ll;
    split2(aa.y, hh, ll); ph[1] = (short)hh; pl[1] = (short)ll;
    split2(aa.z, hh, ll); ph[2] = (short)hh; pl[2] = (short)ll;
    split2(aa.w, hh, ll); ph[3] = (short)hh; pl[3] = (short)ll;
    split2(bb.x, hh, ll); ph[4] = (short)hh; pl[4] = (short)ll;
    split2(bb.y, hh, ll); ph[5] = (short)hh; pl[5] = (short)ll;
    split2(bb.z, hh, ll); ph[6] = (short)hh; pl[6] = (short)ll;
    split2(bb.w, hh, ll); ph[7] = (short)hh; pl[7] = (short)ll;
    Ah[kt] = ph;
    Al[kt] = pl;
  }
  __syncthreads();   // the only barrier

  // ---- L1 (3-term split-bf16 MFMA) + in-register L2 partials ----
  float part[4][5];
#pragma unroll
  for (int r = 0; r < 4; r++)
#pragma unroll
    for (int a = 0; a < NA; a++) part[r][a] = 0.0f;

#pragma unroll
  for (int half = 0; half < 2; half++) {
    f32x4 acc[4];
#pragma unroll
    for (int c2 = 0; c2 < 4; c2++) {
      const float bv = sb1[(half * 4 + c2) * 16 + c16];
      acc[c2] = (f32x4){bv, bv, bv, bv};
    }
#pragma unroll
    for (int kt = 0; kt < 4; kt++) {
#pragma unroll
      for (int c2 = 0; c2 < 4; c2++) {
        const int fb = (half * 4 + c2) * 4 + kt;
        const short8 Bh = *(const short8*)&sW1h[fb * 512 + lane * 8];
        const short8 Bl = *(const short8*)&sW1l[fb * 512 + lane * 8];
        acc[c2] = __builtin_amdgcn_mfma_f32_16x16x32_bf16(Ah[kt], Bh, acc[c2], 0, 0, 0);
        acc[c2] = __builtin_amdgcn_mfma_f32_16x16x32_bf16(Al[kt], Bh, acc[c2], 0, 0, 0);
        acc[c2] = __builtin_amdgcn_mfma_f32_16x16x32_bf16(Ah[kt], Bl, acc[c2], 0, 0, 0);
      }
    }
    // relu + accumulate logit partials (this lane's column slice)
#pragma unroll
    for (int c2 = 0; c2 < 4; c2++) {
      const int ct = half * 4 + c2;
      float w[NA];
#pragma unroll
      for (int a = 0; a < NA; a++) w[a] = sW2t[a][ct * 16 + c16];
#pragma unroll
      for (int r = 0; r < 4; r++) {
        const float hv = fmaxf(acc[c2][r], 0.0f);
#pragma unroll
        for (int a = 0; a < NA; a++) part[r][a] = fmaf(hv, w[a], part[r][a]);
      }
    }
  }

  // ---- butterfly reduce over the 16-lane column group ----
#pragma unroll
  for (int st = 1; st <= 8; st <<= 1) {
#pragma unroll
    for (int r = 0; r < 4; r++)
#pragma unroll
      for (int a = 0; a < NA; a++)
        part[r][a] += __shfl_xor(part[r][a], st);
  }

  // ---- gumbel scores: 20 tasks per 16-lane group (idx = r*5+a) ----
  // task idx0 = c16 (0..15); task idx1 = 16+c16 on lanes c16<4 (all r=3).
  float score0, score1;
  {
    const int r0_ = c16 / 5, a0_ = c16 - 5 * (c16 / 5);
    float lg = 0.0f;
#pragma unroll
    for (int r = 0; r < 4; r++)
#pragma unroll
      for (int a = 0; a < NA; a++)
        if (r0_ == r && a0_ == a) lg = part[r][a];   // static-indexed select
    const float logit = lg + sbp2[a0_];
    const int growr = base + wave * 16 + h2 * 4 + r0_;
    score0 = gumbel_at((uint32_t)(growr * NA + a0_)) + logit;
  }
  {
    const int a1_ = (c16 & 3) + 1;                   // 1..4 (valid on c16<4)
    float lg = 0.0f;
#pragma unroll
    for (int a = 1; a < NA; a++)
      if (a1_ == a) lg = part[3][a];
    const float logit = lg + sbp2[a1_];
    const int growr = base + wave * 16 + h2 * 4 + 3;
    score1 = gumbel_at((uint32_t)(growr * NA + a1_)) + logit;
  }

  // ---- argmax per row (lane c16<4 owns row h2*4 + c16) ----
  int best = 0;
  float bs = 0.0f;
#pragma unroll
  for (int a = 0; a < NA; a++) {
    const int idx = c16 * 5 + a;
    const int src = h2 * 16 + ((idx < 16) ? idx : (idx - 16));
    const float v0 = __shfl(score0, src);
    const float v1 = __shfl(score1, src);
    const float s = (idx < 16) ? v0 : v1;
    if (a == 0) bs = s;
    else if (s > bs) { bs = s; best = a; }   // strict >, first max
  }
  if (c16 < 4) action[base + wave * 16 + h2 * 4 + c16] = best;

  // ---- wemb gather (independent output half, verbatim) ----
#pragma unroll 1
  for (int i = tid; i < 128 * 16; i += 512) {
    const int row = i >> 4, seg = i & 15;
    ((float4*)out_wemb)[(size_t)(base + row) * 16 + seg] =
        ((const float4*)wemb)[(size_t)y[base + row] * 16 + seg];
  }
}

// ---------- Phase 2: self-staging expert (verbatim round-3, proven) ---------
__global__ __launch_bounds__(512, 1) void expert_staged(
    const int* __restrict__ x, const float* __restrict__ cemb,
    const float* __restrict__ We1, const float* __restrict__ be1,
    const float* __restrict__ We2, const float* __restrict__ be2,
    const int* __restrict__ action, float* __restrict__ out) {
  __shared__ __align__(16) ushort sW1[32 * 512];
  __shared__ __align__(16) ushort sW2[16 * 512];
  __shared__ __align__(16) ushort sCt[8][4 * 512];
  __shared__ __align__(16) ushort sHt[8][4 * 512];
  __shared__ __align__(16) float sbe1[NH];
  __shared__ __align__(16) float sbe2[NIW];
  __shared__ int sList[P2_R];
  __shared__ int sCount;

  const int tid = threadIdx.x;
  const int a = blockIdx.x % NA;
  const int chunk = blockIdx.x / NA;
  const int rowBeg = chunk * P2_R;
  const int rowEnd = (rowBeg + P2_R < B_N) ? rowBeg + P2_R : B_N;

  if (tid == 0) sCount = 0;
  __syncthreads();

  for (int r = rowBeg + tid; r < rowEnd; r += 512)
    if (action[r] == a) sList[atomicAdd(&sCount, 1)] = r;

  {
    const float* W1g = We1 + (size_t)a * D2 * NH;
    const int n = tid & 127, q = tid >> 7;
    const int fb = (n >> 4) * 4 + q;
    const int cc = n & 15;
#pragma unroll
    for (int grp = 0; grp < 4; grp++) {
      short8 pk;
#pragma unroll
      for (int j = 0; j < 8; j++)
        pk[j] = (short)f2bf(W1g[(32 * q + 8 * grp + j) * NH + n]);
      *(short8*)&sW1[fb * 512 + (cc + 16 * grp) * 8] = pk;
    }
    if (tid < NH) sbe1[tid] = be1[a * NH + tid];
    if (tid < NIW) sbe2[tid] = be2[a * NIW + tid];
  }
  {
    const float* W2g = We2 + (size_t)a * NH * NIW;
    const int o = tid & 63, hq = tid >> 6;
    const int fb = (o >> 4) * 4 + (hq >> 1);
    const int cc = o & 15;
#pragma unroll
    for (int g2 = 0; g2 < 2; g2++) {
      const int grp = (hq & 1) * 2 + g2;
      short8 pk;
#pragma unroll
      for (int j = 0; j < 8; j++)
        pk[j] = (short)f2bf(W2g[(16 * hq + 8 * g2 + j) * NIW + o]);
      *(short8*)&sW2[fb * 512 + (cc + 16 * grp) * 8] = pk;
    }
  }
  __syncthreads();

  const int cnt = sCount;
  if (cnt == 0) return;

  const int wave = tid >> 6, lane = tid & 63;
  const int rowb = (lane >> 4) * 4;
  ushort* myCt = sCt[wave];
  ushort* myHt = sHt[wave];

#pragma unroll 1
  for (int t16 = wave * 16; t16 < cnt; t16 += 128) {
    {
      const int rt = lane >> 2, q = lane & 3;
      int li = t16 + rt;
      const int g = sList[(li < cnt) ? li : 0];
      const int xi = x[2 * g + (q >> 1)];
      const float4* src = (const float4*)(cemb + (size_t)xi * NIC + (q & 1) * 32);
#pragma unroll
      for (int grp = 0; grp < 4; grp++) {
        const float4 aa = src[2 * grp], bb = src[2 * grp + 1];
        short8 pk;
        pk[0] = (short)f2bf(aa.x); pk[1] = (short)f2bf(aa.y);
        pk[2] = (short)f2bf(aa.z); pk[3] = (short)f2bf(aa.w);
        pk[4] = (short)f2bf(bb.x); pk[5] = (short)f2bf(bb.y);
        pk[6] = (short)f2bf(bb.z); pk[7] = (short)f2bf(bb.w);
        *(short8*)&myCt[q * 512 + (rt + 16 * grp) * 8] = pk;
      }
    }

    short8 A[4];
#pragma unroll
    for (int kt = 0; kt < 4; kt++) A[kt] = *(const short8*)&myCt[kt * 512 + lane * 8];
#pragma unroll
    for (int ct = 0; ct < 8; ct++) {
      const int n = ct * 16 + (lane & 15);
      const float bv = sbe1[n];
      f32x4 acc = {bv, bv, bv, bv};
#pragma unroll
      for (int kt = 0; kt < 4; kt++) {
        const short8 Bf = *(const short8*)&sW1[(ct * 4 + kt) * 512 + lane * 8];
        acc = __builtin_amdgcn_mfma_f32_16x16x32_bf16(A[kt], Bf, acc, 0, 0, 0);
      }
      const int kt2 = n >> 5, grp2 = (n & 31) >> 3, j2 = n & 7;
#pragma unroll
      for (int r = 0; r < 4; r++)
        myHt[kt2 * 512 + ((rowb + r) + 16 * grp2) * 8 + j2] =
            f2bf(fmaxf(acc[r], 0.0f));
    }

    short8 A2[4];
#pragma unroll
    for (int kt = 0; kt < 4; kt++) A2[kt] = *(const short8*)&myHt[kt * 512 + lane * 8];
    int gr4[4];
#pragma unroll
    for (int r = 0; r < 4; r++) {
      const int li2 = t16 + rowb + r;
      gr4[r] = (li2 < cnt) ? sList[li2] : -1;
    }
#pragma unroll
    for (int ot = 0; ot < 4; ot++) {
      const int o = ot * 16 + (lane & 15);
      const float bv = sbe2[o];
      f32x4 o4 = {bv, bv, bv, bv};
#pragma unroll
      for (int kt = 0; kt < 4; kt++) {
        const short8 Bf = *(const short8*)&sW2[(ot * 4 + kt) * 512 + lane * 8];
        o4 = __builtin_amdgcn_mfma_f32_16x16x32_bf16(A2[kt], Bf, o4, 0, 0, 0);
      }
#pragma unroll
      for (int r = 0; r < 4; r++)
        if (gr4[r] >= 0) out[(size_t)gr4[r] * NIW + o] = o4[r];
    }
  }
}

extern "C" void kernel_launch(void* const* d_in, const int* in_sizes, int n_in,
                              void* d_out, int out_size, void* d_ws, size_t ws_size,
                              hipStream_t stream) {
  const int*   x    = (const int*)d_in[0];
  const int*   y    = (const int*)d_in[1];
  const float* cemb = (const float*)d_in[2];
  const float* wemb = (const float*)d_in[3];
  const float* Wp1  = (const float*)d_in[4];
  const float* bp1  = (const float*)d_in[5];
  const float* Wp2  = (const float*)d_in[6];
  const float* bp2  = (const float*)d_in[7];
  const float* We1  = (const float*)d_in[8];
  const float* be1  = (const float*)d_in[9];
  const float* We2  = (const float*)d_in[10];
  const float* be2  = (const float*)d_in[11];

  float* out      = (float*)d_out;
  float* out_wemb = out + (size_t)B_N * NIW;
  int*   action   = (int*)d_ws;   // 256 KB (proven)

  policy_kernel<<<B_N / 128, 512, 0, stream>>>(
      x, y, cemb, wemb, Wp1, bp1, Wp2, bp2, out_wemb, action);
  expert_staged<<<NA * P2_NCHUNK, 512, 0, stream>>>(
      x, cemb, We1, be1, We2, be2, action, out);
}